// Round 4
// baseline (656.413 us; speedup 1.0000x reference)
//
#include <hip/hip_runtime.h>

typedef __attribute__((ext_vector_type(4))) float f4;
typedef __attribute__((ext_vector_type(8))) short s8;

__device__ __forceinline__ unsigned short f2bf(float x){
  unsigned u = __float_as_uint(x);
  u += 0x7fffu + ((u >> 16) & 1u);
  return (unsigned short)(u >> 16);
}
__device__ __forceinline__ float lrelu(float v){ return v > 0.f ? v : 0.2f * v; }

// ---------------- prep 1: zero accumulators + p/q = W @ a_src / a_dst ----------------
__global__ void prep_pq(const float* __restrict__ Wg, const float* __restrict__ a_src,
                        const float* __restrict__ a_dst, float* __restrict__ pq,
                        float* __restrict__ zbase){
  int tid = blockIdx.x * 256 + threadIdx.x;
  for (int i = tid; i < 18444; i += gridDim.x * 256) zbase[i] = 0.f;  // Craw3,Craw1,den,HE2,HE0,B,C
  int wid = tid >> 6, lane = tid & 63;
  for (int task = wid; task < 4096; task += gridDim.x * 4){
    int g = task >> 10, isq = (task >> 9) & 1, r = task & 511;
    const float* w = Wg + ((g * 512 + r) << 9);
    const float* a = (isq ? a_dst : a_src) + g * 512;
    float s = 0.f;
    for (int i = lane; i < 512; i += 64) s += w[i] * a[i];
    for (int off = 32; off; off >>= 1) s += __shfl_down(s, off);
    if (lane == 0) pq[task] = s;
  }
}

// ---------------- prep 2: W2^T, W0^T as bf16 (n-major, contiguous k) ----------------
__global__ void prep_wt(const float* __restrict__ Wg, unsigned short* __restrict__ W2T,
                        unsigned short* __restrict__ W0T){
  __shared__ float tile[32][33];
  const int b = blockIdx.x;
  const int m = b >> 8;                      // 0: W2 -> W2T, 1: W0 -> W0T
  const int kb = (b & 15) * 32;
  const int nb = ((b >> 4) & 15) * 32;
  const float* W = Wg + (m == 0 ? 2 * 262144 : 0);
  unsigned short* WT = (m == 0) ? W2T : W0T;
  const int tx = threadIdx.x & 31, ty = threadIdx.x >> 5;
  #pragma unroll
  for (int i = 0; i < 32; i += 8) tile[ty + i][tx] = W[(kb + ty + i) * 512 + nb + tx];
  __syncthreads();
  #pragma unroll
  for (int i = 0; i < 32; i += 8) WT[(nb + ty + i) * 512 + kb + tx] = f2bf(tile[tx][ty + i]);
}

// ---------------- prep: 48 exercise scalar dots ----------------
__global__ void prep_scal(const float* __restrict__ exer, const float* __restrict__ pq,
                          float* __restrict__ asE, float* __restrict__ adE){
  const int t = threadIdx.x, wid = t >> 6, lane = t & 63;
  for (int task = wid; task < 48; task += 4){
    int gg = task / 12, rem = task % 12, isq = rem / 6, e = rem % 6;
    const float* X = exer + e * 512;
    const float* V = pq + gg * 1024 + isq * 512;
    float s = 0.f;
    for (int i = lane; i < 512; i += 64) s += X[i] * V[i];
    for (int off = 32; off; off >>= 1) s += __shfl_down(s, off);
    if (lane == 0) (isq ? adE : asE)[gg * 6 + e] = s;
  }
}

// ---------------- prep 3 (split-k): HE_g[e] += exer_e[kslice] @ W_g[kslice] ----------------
__global__ void prep_he(const float* __restrict__ exer, const float* __restrict__ Wg,
                        float* __restrict__ HE2, float* __restrict__ HE0){
  const int b = blockIdx.x;           // 0..11
  const int ks = blockIdx.y;          // 0..7
  const int g = (b < 6) ? 0 : 2;
  const int e = b % 6;
  __shared__ float xs[64];
  const int t = threadIdx.x;          // 512
  if (t < 64) xs[t] = exer[e * 512 + ks * 64 + t];
  __syncthreads();
  const float* W = Wg + g * 262144 + ks * 64 * 512;
  float acc = 0.f;
  #pragma unroll 4
  for (int kk = 0; kk < 64; kk++) acc += xs[kk] * W[kk * 512 + t];
  atomicAdd(&((g == 0) ? HE0 : HE2)[e * 512 + t], acc);
}

// ---------------- fused: stage A + per-row GAT scalars + GEMM + epilogue + send-accum ----------------
// Block: 512 thr (8 waves). BM=64 rows, BN=512 (full width, 64 cols/wave).
template<int DEG>
__launch_bounds__(512, 4)
__global__ void fused(const float* __restrict__ x, const unsigned short* __restrict__ WT,
                      const float* __restrict__ pqA, const float* __restrict__ pqB,
                      const float* __restrict__ asEg, const float* __restrict__ adEg,
                      const float* __restrict__ HE, const float* __restrict__ bias,
                      const int* __restrict__ idx, float* __restrict__ Craw,
                      float* __restrict__ den, float* __restrict__ outp, int M)
{
  __shared__ __align__(16) unsigned short sA[32768];   // [64 rows][64 slots of 8 bf16], phys slot s holds k-slot s^(row&7)
  __shared__ float sMeta[64][16];                      // [0]=aself [1..6]=coef_e [7..12]=w_e
  __shared__ float sDot[3][64];

  const int tid = threadIdx.x, lane = tid & 63, w = tid >> 6;
  const int r0 = blockIdx.x * 64;
  const int kseg = (lane ^ w) * 8;   // this lane's fixed k-range for staging/dots (row&7 == w for its rows)

  // preload pq slices for dots (24 regs, dead after phase 1)
  f4 pP0 = *(const f4*)(pqA + kseg),       pP1 = *(const f4*)(pqA + kseg + 4);
  f4 pQ0 = *(const f4*)(pqA + 512 + kseg), pQ1 = *(const f4*)(pqA + 512 + kseg + 4);
  f4 pB0 = *(const f4*)(pqB + kseg),       pB1 = *(const f4*)(pqB + kseg + 4);

  // ---- phase 1: stage A (f32 -> bf16, swizzled) + per-row dot products ----
  #pragma unroll
  for (int i = 0; i < 8; i++){
    const int row = i * 8 + w;                          // row & 7 == w
    const float* xr = x + (size_t)min(r0 + row, M - 1) * 512 + kseg;
    f4 x0 = *(const f4*)(xr), x1 = *(const f4*)(xr + 4);
    float dP = 0.f, dQ = 0.f, dB = 0.f;
    #pragma unroll
    for (int c = 0; c < 4; c++){
      dP += x0[c]*pP0[c] + x1[c]*pP1[c];
      dQ += x0[c]*pQ0[c] + x1[c]*pQ1[c];
      dB += x0[c]*pB0[c] + x1[c]*pB1[c];
    }
    #pragma unroll
    for (int off = 1; off < 64; off <<= 1){
      dP += __shfl_xor(dP, off); dQ += __shfl_xor(dQ, off); dB += __shfl_xor(dB, off);
    }
    if (lane == 0){ sDot[0][row] = dP; sDot[1][row] = dQ; sDot[2][row] = dB; }
    s8 pk;
    #pragma unroll
    for (int c = 0; c < 4; c++){ pk[c] = (short)f2bf(x0[c]); pk[4+c] = (short)f2bf(x1[c]); }
    *(s8*)(sA + row * 512 + lane * 8) = pk;             // linear write; swizzle via kseg source
  }
  __syncthreads();

  // ---- phase 2 (wave 0 only): per-row receive-softmax + send-weights + den ----
  if (w == 0){
    const int r = lane, gr = r0 + r;
    const bool valid = gr < M;
    const float dP = sDot[0][r], dQ = sDot[1][r], dB = sDot[2][r];
    int ei[DEG];
    #pragma unroll
    for (int j = 0; j < DEG; j++) ei[j] = valid ? idx[(size_t)gr * DEG + j] : 0;
    float scS = lrelu(dP + dQ);
    float sc[DEG], m = scS;
    #pragma unroll
    for (int j = 0; j < DEG; j++){ sc[j] = lrelu(asEg[ei[j]] + dQ); m = fmaxf(m, sc[j]); }
    float eS = __expf(scS - m), sum = eS;
    float ev[DEG];
    #pragma unroll
    for (int j = 0; j < DEG; j++){ ev[j] = __expf(sc[j] - m); sum += ev[j]; }
    const float inv = 1.f / sum;
    sMeta[r][0] = valid ? eS * inv : 0.f;
    float wj[DEG];
    #pragma unroll
    for (int j = 0; j < DEG; j++) wj[j] = __expf(lrelu(dB + adEg[ei[j]]));
    #pragma unroll
    for (int e = 0; e < 6; e++){
      float ce = 0.f, we = 0.f;
      #pragma unroll
      for (int j = 0; j < DEG; j++){
        ce += (ei[j] == e) ? ev[j] * inv : 0.f;
        we += (ei[j] == e) ? wj[j] : 0.f;
      }
      sMeta[r][1 + e] = valid ? ce : 0.f;
      we = valid ? we : 0.f;
      sMeta[r][7 + e] = we;
      float t = we;
      #pragma unroll
      for (int off = 1; off < 64; off <<= 1) t += __shfl_xor(t, off);
      if (lane == 0) atomicAdd(den + e, t);
    }
  }

  // ---- K-loop: barrier-free; A from LDS, B streamed from L2-resident WT ----
  const int l16 = lane & 15, lhi = lane >> 4;
  const unsigned short* wtb = WT + (size_t)(w * 64 + l16) * 512 + lhi * 8;
  f4 acc[4][4];
  #pragma unroll
  for (int m = 0; m < 4; m++)
    #pragma unroll
    for (int n = 0; n < 4; n++) acc[m][n] = (f4){0.f, 0.f, 0.f, 0.f};

  #pragma unroll 4
  for (int kt = 0; kt < 16; kt++){
    s8 af[4];
    #pragma unroll
    for (int m = 0; m < 4; m++)
      af[m] = *(const s8*)(sA + (m * 16 + l16) * 512 + ((((kt << 2) | lhi)) ^ (l16 & 7)) * 8);
    #pragma unroll
    for (int n = 0; n < 4; n++){
      s8 bf = *(const s8*)(wtb + (size_t)n * 16 * 512 + kt * 32);
      #pragma unroll
      for (int m = 0; m < 4; m++)
        acc[m][n] = __builtin_amdgcn_mfma_f32_16x16x32_bf16(af[m], bf, acc[m][n], 0, 0, 0);
    }
  }
  __syncthreads();   // sMeta ready + all waves done before epilogue

  // ---- epilogue: out = x + aself*(x@W) + sum_e coef_e*HE[e] + b ; send accum ----
  float hec[4][6], bi[4];
  #pragma unroll
  for (int n = 0; n < 4; n++){
    const int gc = w * 64 + n * 16 + l16;
    bi[n] = bias[gc];
    #pragma unroll
    for (int e = 0; e < 6; e++) hec[n][e] = HE[e * 512 + gc];
  }
  float creg[4][6];
  #pragma unroll
  for (int n = 0; n < 4; n++)
    #pragma unroll
    for (int e = 0; e < 6; e++) creg[n][e] = 0.f;

  #pragma unroll
  for (int m = 0; m < 4; m++){
    #pragma unroll
    for (int j = 0; j < 4; j++){
      const int rl = m * 16 + lhi * 4 + j;
      const int gr = r0 + rl;
      const bool v = gr < M;
      const float aself = sMeta[rl][0];
      float wrow[6], crow[6];
      #pragma unroll
      for (int e = 0; e < 6; e++){ wrow[e] = sMeta[rl][7 + e]; crow[e] = sMeta[rl][1 + e]; }
      #pragma unroll
      for (int n = 0; n < 4; n++){
        const int gc = w * 64 + n * 16 + l16;
        const float xv = v ? x[(size_t)gr * 512 + gc] : 0.f;
        if (v){
          float o = xv + aself * acc[m][n][j] + bi[n];
          #pragma unroll
          for (int e = 0; e < 6; e++) o += crow[e] * hec[n][e];
          outp[(size_t)gr * 512 + gc] = o;
        }
        #pragma unroll
        for (int e = 0; e < 6; e++) creg[n][e] += wrow[e] * xv;
      }
    }
  }
  // reduce send accumulators across lhi groups (rows are partitioned by lhi)
  #pragma unroll
  for (int n = 0; n < 4; n++){
    #pragma unroll
    for (int e = 0; e < 6; e++){
      float vv = creg[n][e];
      vv += __shfl_xor(vv, 16); vv += __shfl_xor(vv, 32);
      if (lhi == 0) atomicAdd(&Craw[e * 512 + w * 64 + n * 16 + l16], vv);
    }
  }
}

// ---------------- finalize B (GAT1) and C (GAT3), split-k ----------------
__global__ void finalize_bc(const float* __restrict__ exer, const float* __restrict__ Wg,
                            const float* __restrict__ asE, const float* __restrict__ adE,
                            const float* __restrict__ Craw3, const float* __restrict__ den3,
                            const float* __restrict__ Craw1, const float* __restrict__ den1,
                            const float* __restrict__ b_gat, float* __restrict__ B,
                            float* __restrict__ C){
  const int b = blockIdx.x;          // 0..11
  const int ks = blockIdx.y;         // 0..7
  const int isC = (b >= 6) ? 1 : 0;
  const int e = b % 6;
  const int g = isC ? 3 : 1;
  const float* Craw = isC ? Craw3 : Craw1;
  const float* den  = isC ? den3  : den1;
  __shared__ float mix[64];
  const int t = threadIdx.x;          // 512
  float aS = asE[g*6 + e], aD = adE[g*6 + e];
  float wself = __expf(lrelu(aS + aD));
  float dn = den[e] + wself;
  if (t < 64){
    int k = ks * 64 + t;
    mix[t] = (Craw[e*512 + k] + wself * exer[e*512 + k]) / dn;
  }
  __syncthreads();
  const float* W = Wg + g * 262144 + ks * 64 * 512;
  float acc = 0.f;
  #pragma unroll 4
  for (int kk = 0; kk < 64; kk++) acc += mix[kk] * W[kk * 512 + t];
  if (ks == 0) acc += b_gat[g*512 + t];
  atomicAdd(&(isC ? C : B)[e*512 + t], acc);
}

// ---------------- final exercise attention + output ----------------
__global__ void finalize_exer(const float* __restrict__ exer, const float* __restrict__ B,
                              const float* __restrict__ C, const float* __restrict__ attn_w,
                              const float* __restrict__ attn_b, float* __restrict__ outE){
  __shared__ float s1[6], s2[6];
  const int t = threadIdx.x, wid = t >> 6, lane = t & 63;
  for (int task = wid; task < 12; task += 8){
    int e = task >> 1, which = task & 1;
    const float* w = attn_w + (which + 1) * 1024;
    const float* X = exer + e * 512;
    const float* Y = (which ? C : B) + e * 512;
    float s = 0.f;
    for (int i = lane; i < 512; i += 64) s += X[i] * w[i] + Y[i] * w[512 + i];
    for (int off = 32; off; off >>= 1) s += __shfl_down(s, off);
    if (lane == 0) (which ? s2 : s1)[e] = s + attn_b[which + 1];
  }
  __syncthreads();
  for (int i = t; i < 3072; i += 512){
    int e = i >> 9;
    float a = s1[e], b = s2[e];
    float m = fmaxf(a, b);
    float ea = __expf(a - m), eb = __expf(b - m);
    float inv = 1.f / (ea + eb);
    outE[i] = exer[i] + (ea * inv) * B[i] + (eb * inv) * C[i];
  }
}

extern "C" void kernel_launch(void* const* d_in, const int* in_sizes, int n_in,
                              void* d_out, int out_size, void* d_ws, size_t ws_size,
                              hipStream_t stream){
  const float* kn     = (const float*)d_in[0];
  const float* exer   = (const float*)d_in[1];
  const float* stu    = (const float*)d_in[2];
  const float* Wg     = (const float*)d_in[3];
  const float* a_src  = (const float*)d_in[4];
  const float* a_dst  = (const float*)d_in[5];
  const float* b_gat  = (const float*)d_in[6];
  const float* attn_w = (const float*)d_in[7];
  const float* attn_b = (const float*)d_in[8];
  const int*   e_ke   = (const int*)d_in[9];
  const int*   e_ue   = (const int*)d_in[11];
  float* out = (float*)d_out;

  unsigned short* W2T = (unsigned short*)d_ws;
  unsigned short* W0T = W2T + 262144;
  float* fb    = (float*)(W0T + 262144);
  float* pq    = fb;                 // 4096
  float* asE   = pq + 4096;          // 24
  float* adE   = asE + 24;           // 24
  float* Craw3 = adE + 24;           // 3072  -- zero region starts here
  float* Craw1 = Craw3 + 3072;       // 3072
  float* den3  = Craw1 + 3072;       // 6
  float* den1  = den3 + 6;           // 6
  float* HE2   = den1 + 6;           // 3072
  float* HE0   = HE2 + 3072;         // 3072
  float* Bb    = HE0 + 3072;         // 3072
  float* Cc    = Bb + 3072;          // 3072  -- zero region = 18444 floats

  hipLaunchKernelGGL(prep_pq, dim3(256), dim3(256), 0, stream, Wg, a_src, a_dst, pq, Craw3);
  hipLaunchKernelGGL(prep_wt, dim3(512), dim3(256), 0, stream, Wg, W2T, W0T);
  hipLaunchKernelGGL(prep_scal, dim3(1), dim3(256), 0, stream, exer, pq, asE, adE);
  hipLaunchKernelGGL(prep_he, dim3(12, 8), dim3(512), 0, stream, exer, Wg, HE2, HE0);

  // fused: students (receive GAT2, send GAT3)
  hipLaunchKernelGGL((fused<3>), dim3(782), dim3(512), 0, stream,
                     stu, W2T, pq + 2048, pq + 3072, asE + 12, adE + 18,
                     HE2, b_gat + 1024, e_ue, Craw3, den3, out + 265216, 50000);
  // fused: knowledge (receive GAT0, send GAT1)
  hipLaunchKernelGGL((fused<4>), dim3(8), dim3(512), 0, stream,
                     kn, W0T, pq, pq + 1024, asE, adE + 6,
                     HE0, b_gat, e_ke, Craw1, den1, out, 512);

  hipLaunchKernelGGL(finalize_bc, dim3(12, 8), dim3(512), 0, stream,
                     exer, Wg, asE, adE, Craw3, den3, Craw1, den1, b_gat, Bb, Cc);
  hipLaunchKernelGGL(finalize_exer, dim3(1), dim3(512), 0, stream,
                     exer, Bb, Cc, attn_w, attn_b, out + 262144);
}

// Round 5
// 403.242 us; speedup vs baseline: 1.6278x; 1.6278x over previous
//
#include <hip/hip_runtime.h>

typedef __attribute__((ext_vector_type(4))) float f4;
typedef __attribute__((ext_vector_type(8))) short s8;

__device__ __forceinline__ unsigned short f2bf(float x){
  unsigned u = __float_as_uint(x);
  u += 0x7fffu + ((u >> 16) & 1u);
  return (unsigned short)(u >> 16);
}
__device__ __forceinline__ float lrelu(float v){ return v > 0.f ? v : 0.2f * v; }
__device__ __forceinline__ void gload16(const unsigned short* g, unsigned short* l){
  __builtin_amdgcn_global_load_lds((const __attribute__((address_space(1))) unsigned int*)g,
                                   (__attribute__((address_space(3))) unsigned int*)l, 16, 0, 0);
}

// ================= K1: merged prep =================
// blocks [0,512): W2/W0 -> bf16 transpose;  [512,768): zero + pq = W @ a;  [768,780): HE = exer @ W
__global__ __launch_bounds__(256) void prep(const float* __restrict__ Wg,
    const float* __restrict__ a_src, const float* __restrict__ a_dst,
    const float* __restrict__ exer, float* __restrict__ pq, float* __restrict__ zbase,
    unsigned short* __restrict__ W2T, unsigned short* __restrict__ W0T,
    float* __restrict__ HE2, float* __restrict__ HE0)
{
  __shared__ float tile[32][33];
  __shared__ float xs[512];
  const int b = blockIdx.x, t = threadIdx.x;
  if (b < 512){
    const int m = b >> 8, kb = (b & 15) * 32, nb = ((b >> 4) & 15) * 32;
    const float* W = Wg + (m == 0 ? 2 * 262144 : 0);
    unsigned short* WT = (m == 0) ? W2T : W0T;
    const int tx = t & 31, ty = t >> 5;
    #pragma unroll
    for (int i = 0; i < 32; i += 8) tile[ty + i][tx] = W[(kb + ty + i) * 512 + nb + tx];
    __syncthreads();
    #pragma unroll
    for (int i = 0; i < 32; i += 8) WT[(nb + ty + i) * 512 + kb + tx] = f2bf(tile[tx][ty + i]);
  } else if (b < 768){
    const int tid = (b - 512) * 256 + t;
    if (tid < 12304) zbase[tid] = 0.f;        // Craw3,Craw1,den3,den1,Bb,Cc
    const int wid = tid >> 6, lane = tid & 63;
    for (int task = wid; task < 4096; task += 1024){
      int g = task >> 10, isq = (task >> 9) & 1, r = task & 511;
      const float* w = Wg + ((g * 512 + r) << 9);
      const float* a = (isq ? a_dst : a_src) + g * 512;
      float s = 0.f;
      for (int i = lane; i < 512; i += 64) s += w[i] * a[i];
      for (int off = 32; off; off >>= 1) s += __shfl_down(s, off);
      if (lane == 0) pq[task] = s;
    }
  } else {
    const int b3 = b - 768;                    // 0..11
    const int g = (b3 < 6) ? 0 : 2, e = b3 % 6;
    xs[t] = exer[e * 512 + t]; xs[t + 256] = exer[e * 512 + 256 + t];
    __syncthreads();
    const float* W = Wg + g * 262144;
    float a0 = 0.f, a1 = 0.f;
    #pragma unroll 8
    for (int k = 0; k < 512; k++){ float xv = xs[k]; a0 += xv * W[k * 512 + t]; a1 += xv * W[k * 512 + 256 + t]; }
    float* HE = (g == 0) ? HE0 : HE2;
    HE[e * 512 + t] = a0; HE[e * 512 + 256 + t] = a1;
  }
}

// ================= K2: pass1 (per-row scalars + send accumulation) =================
template<int DEG>
__device__ void pass1_body(float* sC, float* sDen, float* sASE, float* sADE,
                           int bid, int nblk, const float* __restrict__ x,
                           const float* __restrict__ exer, const float* __restrict__ pq,
                           int gA, int gB, const int* __restrict__ idx,
                           float* __restrict__ alph, float* __restrict__ Craw,
                           float* __restrict__ den, int M)
{
  const int t = threadIdx.x, lane = t & 63, w = t >> 6;
  for (int i = t; i < 3072; i += 256) sC[i] = 0.f;
  if (t < 6) sDen[t] = 0.f;
  // inline 12 scalar dots: sASE[e] = exer_e . pq[gA].src ; sADE[e] = exer_e . pq[gB].dst
  for (int d = w * 3; d < w * 3 + 3; d++){
    const float* X = exer + (d % 6) * 512;
    const float* V = (d < 6) ? (pq + gA * 1024) : (pq + gB * 1024 + 512);
    float s = 0.f;
    for (int i = lane; i < 512; i += 64) s += X[i] * V[i];
    for (int off = 32; off; off >>= 1) s += __shfl_down(s, off);
    if (lane == 0) ((d < 6) ? sASE : sADE)[d % 6] = s;
  }
  __syncthreads();

  const int kb = lane * 8;
  const float* pqA = pq + gA * 1024;
  const float* pqB = pq + gB * 1024;
  f4 pA0 = *(const f4*)(pqA + kb),       pA1 = *(const f4*)(pqA + kb + 4);
  f4 qA0 = *(const f4*)(pqA + 512 + kb), qA1 = *(const f4*)(pqA + 512 + kb + 4);
  f4 pB0 = *(const f4*)(pqB + kb),       pB1 = *(const f4*)(pqB + kb + 4);
  const float aseR = sASE[lane % 6];
  const float adeR = sADE[lane % 6];

  float cacc[6][8];
  #pragma unroll
  for (int e = 0; e < 6; e++)
    #pragma unroll
    for (int i = 0; i < 8; i++) cacc[e][i] = 0.f;
  float dacc[6] = {0.f,0.f,0.f,0.f,0.f,0.f};

  const int gw = bid * 4 + w, nw = nblk * 4;
  for (int r = gw; r < M; r += nw){
    const float* xr = x + (size_t)r * 512;
    f4 x0 = *(const f4*)(xr + kb), x1 = *(const f4*)(xr + kb + 4);
    float dP = 0.f, dQ = 0.f, dB = 0.f;
    #pragma unroll
    for (int i = 0; i < 4; i++){
      dP += x0[i]*pA0[i] + x1[i]*pA1[i];
      dQ += x0[i]*qA0[i] + x1[i]*qA1[i];
      dB += x0[i]*pB0[i] + x1[i]*pB1[i];
    }
    #pragma unroll
    for (int off = 1; off < 64; off <<= 1){
      dP += __shfl_xor(dP, off); dQ += __shfl_xor(dQ, off); dB += __shfl_xor(dB, off);
    }
    int ei[DEG];
    #pragma unroll
    for (int j = 0; j < DEG; j++) ei[j] = idx[r * DEG + j];
    float scS = lrelu(dP + dQ);
    float sc[DEG], m = scS;
    #pragma unroll
    for (int j = 0; j < DEG; j++){ sc[j] = lrelu(__shfl(aseR, ei[j]) + dQ); m = fmaxf(m, sc[j]); }
    float eS = __expf(scS - m), sum = eS;
    float ev[DEG];
    #pragma unroll
    for (int j = 0; j < DEG; j++){ ev[j] = __expf(sc[j] - m); sum += ev[j]; }
    float inv = 1.f / sum;
    float val = 0.f;
    if (lane == 0) val = eS * inv;
    else if (lane < 7){
      #pragma unroll
      for (int j = 0; j < DEG; j++) val += (ei[j] == lane - 1) ? ev[j] * inv : 0.f;
    }
    if (lane < 8) alph[(size_t)r * 8 + lane] = val;
    float wj[DEG];
    #pragma unroll
    for (int j = 0; j < DEG; j++) wj[j] = __expf(lrelu(dB + __shfl(adeR, ei[j])));
    #pragma unroll
    for (int e = 0; e < 6; e++){
      float we = 0.f;
      #pragma unroll
      for (int j = 0; j < DEG; j++) we += (ei[j] == e) ? wj[j] : 0.f;
      dacc[e] += we;
      #pragma unroll
      for (int i = 0; i < 4; i++){ cacc[e][i] += we * x0[i]; cacc[e][4+i] += we * x1[i]; }
    }
  }
  #pragma unroll
  for (int e = 0; e < 6; e++)
    #pragma unroll
    for (int i = 0; i < 8; i++)
      atomicAdd(&sC[e * 512 + kb + i], cacc[e][i]);
  if (lane == 0){
    #pragma unroll
    for (int e = 0; e < 6; e++) atomicAdd(&sDen[e], dacc[e]);
  }
  __syncthreads();
  for (int i = t; i < 3072; i += 256){
    float v = sC[i];
    if (v != 0.f) atomicAdd(&Craw[i], v);
  }
  if (t < 6) atomicAdd(&den[t], sDen[t]);
}

__global__ __launch_bounds__(256) void pass1_all(const float* __restrict__ stu,
    const float* __restrict__ kn, const float* __restrict__ exer,
    const float* __restrict__ pq, const int* __restrict__ e_ue, const int* __restrict__ e_ke,
    float* __restrict__ alphS, float* __restrict__ alphK,
    float* __restrict__ Craw3, float* __restrict__ Craw1,
    float* __restrict__ den3, float* __restrict__ den1)
{
  __shared__ float sC[3072];
  __shared__ float sDen[6], sASE[6], sADE[6];
  if (blockIdx.x < 768)
    pass1_body<3>(sC, sDen, sASE, sADE, blockIdx.x, 768, stu, exer, pq, 2, 3,
                  e_ue, alphS, Craw3, den3, 50000);
  else
    pass1_body<4>(sC, sDen, sASE, sADE, blockIdx.x - 768, 8, kn, exer, pq, 0, 1,
                  e_ke, alphK, Craw1, den1, 512);
}

// ================= K3: m97-style GEMM (BM=128,BN=128,BK=32, 2-phase) + fused epilogue =================
__launch_bounds__(256, 3)
__global__ void gemm_all(const float* __restrict__ stu, const float* __restrict__ kn,
                         const unsigned short* __restrict__ W2T, const unsigned short* __restrict__ W0T,
                         const float* __restrict__ alphS, const float* __restrict__ alphK,
                         const float* __restrict__ HE2, const float* __restrict__ HE0,
                         const float* __restrict__ b_gat, float* __restrict__ outS,
                         float* __restrict__ outK)
{
  __shared__ __align__(16) unsigned short sA[8192];   // 2 bufs x [128 rows][4 slots of 8], slot^=(row>>1)&3
  __shared__ __align__(16) unsigned short sB[8192];
  __shared__ __align__(16) float sAl[1024];
  __shared__ __align__(16) float sHEb[768];
  __shared__ __align__(16) float sBias[128];

  // bijective XCD chunking, nb-fastest within each mb
  const int nwg = gridDim.x;
  const int q = nwg >> 3, rr = nwg & 7;
  const int xcd = blockIdx.x & 7, pos = blockIdx.x >> 3;
  const int wido = (xcd < rr ? xcd * (q + 1) : rr * (q + 1) + (xcd - rr) * q) + pos;

  const float* x; const unsigned short* WT; const float* alph; const float* HE;
  const float* bias; float* outp; int M, mb, nb;
  if (wido < 1564){
    x = stu; WT = W2T; alph = alphS; HE = HE2; bias = b_gat + 1024; outp = outS; M = 50000;
    mb = wido >> 2; nb = wido & 3;
  } else {
    const int w2 = wido - 1564;
    x = kn; WT = W0T; alph = alphK; HE = HE0; bias = b_gat; outp = outK; M = 512;
    mb = w2 >> 2; nb = w2 & 3;
  }
  const int r0 = mb * 128, n0 = nb * 128;
  const int tid = threadIdx.x, lane = tid & 63, w = tid >> 6;
  const int wr = w >> 1, wc = w & 1, l16 = lane & 15, lhi = lane >> 4;

  // A staging: thread -> row=tid>>1, half=(tid&1)
  const int arow = tid >> 1, akh = (tid & 1) * 16;
  const float* aptr = x + (size_t)min(r0 + arow, M - 1) * 512 + akh;
  const int akey = (arow >> 1) & 3, s0 = (tid & 1) * 2;
  const int dA0 = arow * 32 + ((s0 ^ akey) << 3);
  const int dA1 = arow * 32 + (((s0 + 1) ^ akey) << 3);

  // B staging: thread -> row=tid>>2 (+64), slot=tid&3; source pre-swizzled
  const int brow = tid >> 2, bslot = tid & 3;
  const int bkey = (brow >> 1) & 3;
  const unsigned short* gB0 = WT + (size_t)(n0 + brow) * 512 + ((bslot ^ bkey) << 3);
  const unsigned short* gB1 = gB0 + (size_t)64 * 512;
  unsigned short* lB0 = sB + tid * 8;
  unsigned short* lB1 = sB + 2048 + tid * 8;

  // reader offsets (invariant across kt)
  int aoff[4], boff[4];
  #pragma unroll
  for (int m = 0; m < 4; m++){
    const int ra = wr * 64 + m * 16 + l16;
    aoff[m] = ra * 32 + ((lhi ^ ((ra >> 1) & 3)) << 3);
    const int rb = wc * 64 + m * 16 + l16;
    boff[m] = rb * 32 + ((lhi ^ ((rb >> 1) & 3)) << 3);
  }

  // ---- prologue: stage kt=0 + aux ----
  gload16(gB0, lB0); gload16(gB1, lB1);
  f4 c0 = *(const f4*)(aptr),     c1 = *(const f4*)(aptr + 4);
  f4 c2 = *(const f4*)(aptr + 8), c3 = *(const f4*)(aptr + 12);
  {
    s8 p0, p1;
    #pragma unroll
    for (int i = 0; i < 4; i++){
      p0[i] = (short)f2bf(c0[i]); p0[4+i] = (short)f2bf(c1[i]);
      p1[i] = (short)f2bf(c2[i]); p1[4+i] = (short)f2bf(c3[i]);
    }
    *(s8*)(sA + dA0) = p0; *(s8*)(sA + dA1) = p1;
  }
  { const int rw = min(r0 + (tid >> 1), M - 1);
    *(f4*)(sAl + tid * 4) = *(const f4*)(alph + (size_t)rw * 8 + (tid & 1) * 4); }
  if (tid < 192) *(f4*)(sHEb + tid * 4) = *(const f4*)(HE + (tid >> 5) * 512 + n0 + (tid & 31) * 4);
  else if (tid < 224){ const int i2 = tid - 192; *(f4*)(sBias + i2 * 4) = *(const f4*)(bias + n0 + i2 * 4); }
  __syncthreads();

  f4 acc[4][4];
  #pragma unroll
  for (int m = 0; m < 4; m++)
    #pragma unroll
    for (int n = 0; n < 4; n++) acc[m][n] = (f4){0.f, 0.f, 0.f, 0.f};

  int bufo = 0;
  #pragma unroll 1
  for (int kt = 0; kt < 16; kt++){
    const int nxt = bufo ^ 4096;
    if (kt < 15){
      gload16(gB0 + (kt + 1) * 32, lB0 + nxt);
      gload16(gB1 + (kt + 1) * 32, lB1 + nxt);
      c0 = *(const f4*)(aptr + (kt + 1) * 32);     c1 = *(const f4*)(aptr + (kt + 1) * 32 + 4);
      c2 = *(const f4*)(aptr + (kt + 1) * 32 + 8); c3 = *(const f4*)(aptr + (kt + 1) * 32 + 12);
    }
    s8 af[4], bf[4];
    #pragma unroll
    for (int m = 0; m < 4; m++) af[m] = *(const s8*)(sA + bufo + aoff[m]);
    #pragma unroll
    for (int n = 0; n < 4; n++) bf[n] = *(const s8*)(sB + bufo + boff[n]);
    #pragma unroll
    for (int m = 0; m < 4; m++)
      #pragma unroll
      for (int n = 0; n < 4; n++)
        acc[m][n] = __builtin_amdgcn_mfma_f32_16x16x32_bf16(af[m], bf[n], acc[m][n], 0, 0, 0);
    if (kt < 15){
      s8 p0, p1;
      #pragma unroll
      for (int i = 0; i < 4; i++){
        p0[i] = (short)f2bf(c0[i]); p0[4+i] = (short)f2bf(c1[i]);
        p1[i] = (short)f2bf(c2[i]); p1[4+i] = (short)f2bf(c3[i]);
      }
      *(s8*)(sA + nxt + dA0) = p0; *(s8*)(sA + nxt + dA1) = p1;
    }
    __syncthreads();
    bufo = nxt;
  }

  // ---- epilogue: out = x + a_self*(x@W) + sum_e coef_e*HE[e] + b ----
  float hec[4][6], bi[4];
  #pragma unroll
  for (int n = 0; n < 4; n++){
    const int cl = wc * 64 + n * 16 + l16;
    bi[n] = sBias[cl];
    #pragma unroll
    for (int e = 0; e < 6; e++) hec[n][e] = sHEb[e * 128 + cl];
  }
  #pragma unroll
  for (int m = 0; m < 4; m++){
    #pragma unroll
    for (int j = 0; j < 4; j++){
      const int rl = wr * 64 + m * 16 + lhi * 4 + j;
      const int gr = r0 + rl;
      if (gr < M){
        f4 alA = *(const f4*)(sAl + rl * 8);
        f4 alB = *(const f4*)(sAl + rl * 8 + 4);
        #pragma unroll
        for (int n = 0; n < 4; n++){
          const int gc = n0 + wc * 64 + n * 16 + l16;
          float v = x[(size_t)gr * 512 + gc] + alA[0] * acc[m][n][j] + bi[n];
          v += alA[1] * hec[n][0] + alA[2] * hec[n][1] + alA[3] * hec[n][2];
          v += alB[0] * hec[n][3] + alB[1] * hec[n][4] + alB[2] * hec[n][5];
          outp[(size_t)gr * 512 + gc] = v;
        }
      }
    }
  }
}

// ================= K4: finalize B (GAT1) / C (GAT3), split-k, inline scalars =================
__global__ __launch_bounds__(512) void fin_bc(const float* __restrict__ exer,
    const float* __restrict__ Wg, const float* __restrict__ pq,
    const float* __restrict__ Craw3, const float* __restrict__ den3,
    const float* __restrict__ Craw1, const float* __restrict__ den1,
    const float* __restrict__ b_gat, float* __restrict__ B, float* __restrict__ C)
{
  const int b = blockIdx.x, ks = blockIdx.y;
  const int isC = (b >= 6) ? 1 : 0, e = b % 6, g = isC ? 3 : 1;
  const float* Craw = isC ? Craw3 : Craw1;
  const float* den  = isC ? den3  : den1;
  __shared__ float mix[64];
  __shared__ float sdots[2];
  const int t = threadIdx.x, lane = t & 63, w = t >> 6;
  if (w < 2){
    const float* V = pq + g * 1024 + w * 512;
    const float* X = exer + e * 512;
    float s = 0.f;
    for (int i = lane; i < 512; i += 64) s += X[i] * V[i];
    for (int off = 32; off; off >>= 1) s += __shfl_down(s, off);
    if (lane == 0) sdots[w] = s;
  }
  __syncthreads();
  const float wself = __expf(lrelu(sdots[0] + sdots[1]));
  const float dn = den[e] + wself;
  if (t < 64){
    const int k = ks * 64 + t;
    mix[t] = (Craw[e * 512 + k] + wself * exer[e * 512 + k]) / dn;
  }
  __syncthreads();
  const float* W = Wg + g * 262144 + ks * 64 * 512;
  float acc = 0.f;
  #pragma unroll 4
  for (int kk = 0; kk < 64; kk++) acc += mix[kk] * W[kk * 512 + t];
  if (ks == 0) acc += b_gat[g * 512 + t];
  atomicAdd(&(isC ? C : B)[e * 512 + t], acc);
}

// ================= K5: final exercise attention =================
__global__ __launch_bounds__(512) void fin_exer(const float* __restrict__ exer,
    const float* __restrict__ B, const float* __restrict__ C,
    const float* __restrict__ attn_w, const float* __restrict__ attn_b,
    float* __restrict__ outE)
{
  __shared__ float s1[6], s2[6];
  const int t = threadIdx.x, wid = t >> 6, lane = t & 63;
  for (int task = wid; task < 12; task += 8){
    int e = task >> 1, which = task & 1;
    const float* w = attn_w + (which + 1) * 1024;
    const float* X = exer + e * 512;
    const float* Y = (which ? C : B) + e * 512;
    float s = 0.f;
    for (int i = lane; i < 512; i += 64) s += X[i] * w[i] + Y[i] * w[512 + i];
    for (int off = 32; off; off >>= 1) s += __shfl_down(s, off);
    if (lane == 0) (which ? s2 : s1)[e] = s + attn_b[which + 1];
  }
  __syncthreads();
  for (int i = t; i < 3072; i += 512){
    int e = i >> 9;
    float a = s1[e], b = s2[e];
    float m = fmaxf(a, b);
    float ea = __expf(a - m), eb = __expf(b - m);
    float inv = 1.f / (ea + eb);
    outE[i] = exer[i] + (ea * inv) * B[i] + (eb * inv) * C[i];
  }
}

extern "C" void kernel_launch(void* const* d_in, const int* in_sizes, int n_in,
                              void* d_out, int out_size, void* d_ws, size_t ws_size,
                              hipStream_t stream){
  const float* kn     = (const float*)d_in[0];
  const float* exer   = (const float*)d_in[1];
  const float* stu    = (const float*)d_in[2];
  const float* Wg     = (const float*)d_in[3];
  const float* a_src  = (const float*)d_in[4];
  const float* a_dst  = (const float*)d_in[5];
  const float* b_gat  = (const float*)d_in[6];
  const float* attn_w = (const float*)d_in[7];
  const float* attn_b = (const float*)d_in[8];
  const int*   e_ke   = (const int*)d_in[9];
  const int*   e_ue   = (const int*)d_in[11];
  float* out = (float*)d_out;

  unsigned short* W2T = (unsigned short*)d_ws;
  unsigned short* W0T = W2T + 262144;
  float* pq    = (float*)(W0T + 262144);   // 4096
  float* Craw3 = pq + 4096;                // 3072  -- zero region (12304 floats)
  float* Craw1 = Craw3 + 3072;             // 3072
  float* den3  = Craw1 + 3072;             // 8
  float* den1  = den3 + 8;                 // 8
  float* Bb    = den1 + 8;                 // 3072
  float* Cc    = Bb + 3072;                // 3072  -- zero region end
  float* HE2   = Cc + 3072;                // 3072
  float* HE0   = HE2 + 3072;               // 3072
  float* alphS = HE0 + 3072;               // 400384
  float* alphK = alphS + 400384;           // 4096

  hipLaunchKernelGGL(prep, dim3(780), dim3(256), 0, stream,
                     Wg, a_src, a_dst, exer, pq, Craw3, W2T, W0T, HE2, HE0);
  hipLaunchKernelGGL(pass1_all, dim3(776), dim3(256), 0, stream,
                     stu, kn, exer, pq, e_ue, e_ke, alphS, alphK, Craw3, Craw1, den3, den1);
  hipLaunchKernelGGL(gemm_all, dim3(1580), dim3(256), 0, stream,
                     stu, kn, W2T, W0T, alphS, alphK, HE2, HE0, b_gat, out + 265216, out);
  hipLaunchKernelGGL(fin_bc, dim3(12, 8), dim3(512), 0, stream,
                     exer, Wg, pq, Craw3, den3, Craw1, den1, b_gat, Bb, Cc);
  hipLaunchKernelGGL(fin_exer, dim3(1), dim3(512), 0, stream,
                     exer, Bb, Cc, attn_w, attn_b, out + 262144);
}